// Round 8
// baseline (1170.183 us; speedup 1.0000x reference)
//
#include <hip/hip_runtime.h>

#define Bsz 1024
#define Tt  256
#define Vv  32004
#define Dd  50
#define Hh  64
#define RR  32   // vocab rows per build_tables block

typedef __bf16 b16x8 __attribute__((ext_vector_type(8)));
typedef __bf16 b16x4 __attribute__((ext_vector_type(4)));
typedef float  f32x4 __attribute__((ext_vector_type(4)));

// barrier WITHOUT vmcnt(0) drain: LDS ordering only; in-flight global loads
// (the xw register prefetch) survive across it.
__device__ __forceinline__ void barrier_novm() {
    asm volatile("s_waitcnt lgkmcnt(0)\n\ts_barrier" ::: "memory");
}
__device__ __forceinline__ float fsig(float x) {
    return __fdividef(1.0f, 1.0f + __expf(-x));
}
__device__ __forceinline__ float ftanh(float x) {
    return 2.0f * __fdividef(1.0f, 1.0f + __expf(-2.0f * x)) - 1.0f;
}

// ---------------------------------------------------------------------------
// Prologue: tab[v][g] = sum_d emb[v][d] * Wih[g][d] + bih[g] + bhh[g]
// v4: wpack TRANSPOSED to [g][13] float4 (stride 13 -> word bank (20g+4j)%32,
// distinct per g-octet -> conflict-free b128 reads; old [j][256] layout was
// 8-way conflicted on every one of the 52 reads/thread). emb tile in LDS,
// broadcast float4 reads (same addr across wave = free).
// ---------------------------------------------------------------------------
__launch_bounds__(256, 2)
__global__ void build_tables(const float* __restrict__ emb,
                             const float* __restrict__ Wih1,
                             const float* __restrict__ bih1,
                             const float* __restrict__ bhh1,
                             const float* __restrict__ Wih2,
                             const float* __restrict__ bih2,
                             const float* __restrict__ bhh2,
                             float* __restrict__ tab1,
                             float* __restrict__ tab2) {
    const int v0 = blockIdx.x * RR;
    const int g  = threadIdx.x;
    const int nr = min(RR, Vv - v0);

    const float* Wih = blockIdx.y ? Wih2 : Wih1;
    const float* bih = blockIdx.y ? bih2 : bih1;
    const float* bhh = blockIdx.y ? bhh2 : bhh1;
    float*       tab = blockIdx.y ? tab2 : tab1;

    __shared__ __align__(16) float4 wpack[256 * 13];   // [g][j], 53.2 KB
    __shared__ __align__(16) float  elds[RR * 52];     // 6.66 KB

    {
        const float* wrow = Wih + (size_t)g * Dd;
#pragma unroll
        for (int j = 0; j < 12; ++j) {
            const float2 a = *(const float2*)(wrow + 4 * j);
            const float2 b = *(const float2*)(wrow + 4 * j + 2);
            wpack[g * 13 + j] = make_float4(a.x, a.y, b.x, b.y);
        }
        const float2 t = *(const float2*)(wrow + 48);
        wpack[g * 13 + 12] = make_float4(t.x, t.y, 0.0f, 0.0f);
    }
    for (int i = threadIdx.x; i < nr * 52; i += 256) {
        const int row = i / 52;
        const int col = i - row * 52;
        elds[i] = (col < Dd) ? emb[(size_t)(v0 + row) * Dd + col] : 0.0f;
    }
    __syncthreads();

    const float bias = bih[g] + bhh[g];

    for (int cc = 0; cc < RR / 8; ++cc) {
        const int r0 = cc * 8;
        float acc[8];
#pragma unroll
        for (int r = 0; r < 8; ++r) acc[r] = 0.0f;
#pragma unroll
        for (int j = 0; j < 13; ++j) {
            const float4 wv = wpack[g * 13 + j];        // conflict-free b128
#pragma unroll
            for (int r = 0; r < 8; ++r) {
                const float4 e = *(const float4*)(&elds[(r0 + r) * 52 + 4 * j]);
                acc[r] += e.x * wv.x + e.y * wv.y + e.z * wv.z + e.w * wv.w;
            }
        }
#pragma unroll
        for (int r = 0; r < 8; ++r) {
            if (r0 + r < nr)
                tab[(size_t)(v0 + r0 + r) * 256 + g] = acc[r] + bias;
        }
    }
}

// ---------------------------------------------------------------------------
// MFMA recurrence v3: 256 blocks x 4 batch rows x 4 waves, gates stay in regs.
// Wave w computes m-tiles {w, 4+w, 8+w, 12+w}: tile (4j+w) covers gates
// 64j + 16w + [0,16). C layout (row=4q+reg, col=lane&15) => lane (n=mn, q)
// holds i/f/g/o of hid = 16w+4q+r, row mn in acc[j=0..3][r] -- the update is
// REGISTER-LOCAL (no gate LDS exchange at all). One lgkm-barrier per step for
// the h publish (hsh double-buffered on parity). xw = 4x global dwordx4 from
// the exact fp32 token table, prefetched one step ahead (survives barrier).
// ---------------------------------------------------------------------------
__launch_bounds__(256, 1)
__global__ void lstm_main(const int*   __restrict__ s1,
                          const int*   __restrict__ s2,
                          const int*   __restrict__ len1,
                          const int*   __restrict__ len2,
                          const float* __restrict__ tab1,
                          const float* __restrict__ tab2,
                          const float* __restrict__ Whh1,
                          const float* __restrict__ Whh2,
                          const float* __restrict__ Wl1,
                          const float* __restrict__ bl1,
                          const float* __restrict__ Wl2,
                          const float* __restrict__ bl2,
                          float* __restrict__ out) {
    const int tid  = threadIdx.x;
    const int w    = tid >> 6;          // wave id
    const int lane = tid & 63;
    const int q    = lane >> 4;         // MFMA quad
    const int mn   = lane & 15;         // A-m / B-n / C-col index
    const int b0   = blockIdx.x * 4;    // 4 batch rows per block

    const bool owner = mn < 4;          // update owners: row = mn
    const int  gate0 = 16 * w + 4 * q;  // hid base for this lane (r = 0..3)

    __shared__ __bf16 hsh[2][16][72];   // [parity][row][hid], pad 72
    __shared__ int    toklds[4][260];
    __shared__ float  h2s[4][64];
    __shared__ float  ys[4][128];

    float c[4]  = {0.f, 0.f, 0.f, 0.f};
    float selh[4] = {0.f, 0.f, 0.f, 0.f};
    float selc[4] = {0.f, 0.f, 0.f, 0.f};
    const f32x4 zero4 = {0.0f, 0.0f, 0.0f, 0.0f};

    for (int phase = 0; phase < 2; ++phase) {
        const float* tab  = phase ? tab2 : tab1;
        const float* Whh  = phase ? Whh2 : Whh1;
        const int*   sent = phase ? s2 : s1;
        const int*   lenp = phase ? len2 : len1;

        // ---- stage this block's tokens (4 rows x 256, coalesced)
        for (int i = tid; i < 4 * Tt; i += 256) {
            const int r = i >> 8, t = i & (Tt - 1);
            toklds[r][t] = sent[(size_t)(b0 + r) * Tt + t];
        }

        // ---- A-frags: tile (4j+w), A[m=mn][k=32kh+8q+jj], fp32->bf16 once
        b16x8 af[4][2];
#pragma unroll
        for (int j = 0; j < 4; ++j) {
            const int gate = 64 * j + 16 * w + mn;
#pragma unroll
            for (int kh = 0; kh < 2; ++kh) {
                const float* ar = Whh + (size_t)gate * Hh + kh * 32 + q * 8;
                const float4 f0 = *(const float4*)ar;
                const float4 f1 = *(const float4*)(ar + 4);
                b16x8 a;
                a[0] = (__bf16)f0.x; a[1] = (__bf16)f0.y;
                a[2] = (__bf16)f0.z; a[3] = (__bf16)f0.w;
                a[4] = (__bf16)f1.x; a[5] = (__bf16)f1.y;
                a[6] = (__bf16)f1.z; a[7] = (__bf16)f1.w;
                af[j][kh] = a;
            }
        }

        // ---- per-owner state: gather indices + seed h
        int4 mi = make_int4(-2, -2, -2, -2);
        if (owner) {
            mi = *(const int4*)&lenp[(size_t)(b0 + mn) * Hh + gate0];
            float hseed[4];
#pragma unroll
            for (int r = 0; r < 4; ++r) {
                hseed[r] = phase ? selh[r] : 0.0f;
                c[r]     = phase ? selc[r] : 0.0f;
            }
            b16x4 hv;
#pragma unroll
            for (int r = 0; r < 4; ++r) hv[r] = (__bf16)hseed[r];
            *(b16x4*)&hsh[0][mn][gate0] = hv;   // t=0 reads parity 0
        }
#pragma unroll
        for (int r = 0; r < 4; ++r) { selh[r] = 0.0f; selc[r] = 0.0f; }
        __syncthreads();   // full drain at phase start (also vmcnt)

        // ---- xw prefetch for t=0
        f32x4 SA[4], SB[4];
        if (owner) {
            const int tk = toklds[mn][0];
            const float* tr = tab + (size_t)tk * 256 + gate0;
            SA[0] = *(const f32x4*)(tr);
            SA[1] = *(const f32x4*)(tr + 64);
            SA[2] = *(const f32x4*)(tr + 128);
            SA[3] = *(const f32x4*)(tr + 192);
        }

        auto step = [&](int t, f32x4* Scur, f32x4* Snext) {
            const int p = t & 1;
            // B frags: B[k=8q+jj][n=mn] from hsh[p][mn]
            const b16x8 bf0 = *(const b16x8*)&hsh[p][mn][q * 8];
            const b16x8 bf1 = *(const b16x8*)&hsh[p][mn][32 + q * 8];

            // prefetch xw(t+1): issued early, consumed after next barrier
            if (owner) {
                const int tk = toklds[mn][(t + 1 < Tt) ? t + 1 : Tt - 1];
                const float* tr = tab + (size_t)tk * 256 + gate0;
                Snext[0] = *(const f32x4*)(tr);
                Snext[1] = *(const f32x4*)(tr + 64);
                Snext[2] = *(const f32x4*)(tr + 128);
                Snext[3] = *(const f32x4*)(tr + 192);
            }

            f32x4 ac0 = __builtin_amdgcn_mfma_f32_16x16x32_bf16(af[0][0], bf0, zero4, 0, 0, 0);
            ac0       = __builtin_amdgcn_mfma_f32_16x16x32_bf16(af[0][1], bf1, ac0,   0, 0, 0);
            f32x4 ac1 = __builtin_amdgcn_mfma_f32_16x16x32_bf16(af[1][0], bf0, zero4, 0, 0, 0);
            ac1       = __builtin_amdgcn_mfma_f32_16x16x32_bf16(af[1][1], bf1, ac1,   0, 0, 0);
            f32x4 ac2 = __builtin_amdgcn_mfma_f32_16x16x32_bf16(af[2][0], bf0, zero4, 0, 0, 0);
            ac2       = __builtin_amdgcn_mfma_f32_16x16x32_bf16(af[2][1], bf1, ac2,   0, 0, 0);
            f32x4 ac3 = __builtin_amdgcn_mfma_f32_16x16x32_bf16(af[3][0], bf0, zero4, 0, 0, 0);
            ac3       = __builtin_amdgcn_mfma_f32_16x16x32_bf16(af[3][1], bf1, ac3,   0, 0, 0);

            if (owner) {
                b16x4 hv;
                const int midx[4] = {mi.x, mi.y, mi.z, mi.w};
#pragma unroll
                for (int r = 0; r < 4; ++r) {
                    const float gI = ac0[r] + Scur[0][r];
                    const float gF = ac1[r] + Scur[1][r];
                    const float gG = ac2[r] + Scur[2][r];
                    const float gO = ac3[r] + Scur[3][r];
                    const float iv = fsig(gI);
                    const float fv = fsig(gF);
                    const float gv = ftanh(gG);
                    const float ov = fsig(gO);
                    c[r] = fv * c[r] + iv * gv;
                    const float h = ov * ftanh(c[r]);
                    if (t == midx[r]) { selh[r] = h; selc[r] = c[r]; }
                    hv[r] = (__bf16)h;
                }
                *(b16x4*)&hsh[p ^ 1][mn][gate0] = hv;  // publish h for t+1
            }
            barrier_novm();   // the ONE barrier (lgkm only)
        };

        for (int t = 0; t < Tt; t += 2) {
            step(t,     SA, SB);
            step(t + 1, SB, SA);
        }
    }

    // ---------------- epilogue MLP on the 4 gathered rows -------------------
    if (owner) *(f32x4*)&h2s[mn][gate0] = *(f32x4*)selh;
    __syncthreads();
#pragma unroll
    for (int pp = 0; pp < 2; ++pp) {
        const int idx = tid + 256 * pp;        // 512 (row, neuron) tasks
        const int rr = idx >> 7, nn = idx & 127;
        float a = bl1[nn];
        const float* wl = Wl1 + nn * 64;
#pragma unroll 8
        for (int k = 0; k < 64; ++k) a += h2s[rr][k] * wl[k];
        ys[rr][nn] = ftanh(a);
    }
    __syncthreads();
    if (tid < 16) {
        const int rr = tid >> 2, o = tid & 3;
        float a = bl2[o];
        const float* wl = Wl2 + o * 128;
#pragma unroll 8
        for (int k = 0; k < 128; ++k) a += ys[rr][k] * wl[k];
        out[(size_t)(b0 + rr) * 4 + o] = a;
    }
}

// ---------------------------------------------------------------------------
extern "C" void kernel_launch(void* const* d_in, const int* in_sizes, int n_in,
                              void* d_out, int out_size, void* d_ws, size_t ws_size,
                              hipStream_t stream) {
    const int*   s1   = (const int*)d_in[0];
    const int*   s2   = (const int*)d_in[1];
    const int*   l1   = (const int*)d_in[2];
    const int*   l2   = (const int*)d_in[3];
    // d_in[4], d_in[5] (s1_s, s2_s) unused by the reference
    const float* emb  = (const float*)d_in[6];
    const float* Wih1 = (const float*)d_in[7];
    const float* Whh1 = (const float*)d_in[8];
    const float* bih1 = (const float*)d_in[9];
    const float* bhh1 = (const float*)d_in[10];
    const float* Wih2 = (const float*)d_in[11];
    const float* Whh2 = (const float*)d_in[12];
    const float* bih2 = (const float*)d_in[13];
    const float* bhh2 = (const float*)d_in[14];
    const float* Wl1  = (const float*)d_in[15];
    const float* bl1  = (const float*)d_in[16];
    const float* Wl2  = (const float*)d_in[17];
    const float* bl2  = (const float*)d_in[18];
    float* out = (float*)d_out;

    float* tab1 = (float*)d_ws;                       // [V,256] fp32
    float* tab2 = tab1 + (size_t)Vv * 256;            // [V,256] fp32  (65.6 MB)

    dim3 grid((Vv + RR - 1) / RR, 2);
    build_tables<<<grid, 256, 0, stream>>>(emb, Wih1, bih1, bhh1,
                                           Wih2, bih2, bhh2, tab1, tab2);
    lstm_main<<<Bsz / 4, 256, 0, stream>>>(s1, s2, l1, l2, tab1, tab2,
                                           Whh1, Whh2, Wl1, bl1, Wl2, bl2, out);
}

// Round 9
// 495.961 us; speedup vs baseline: 2.3594x; 2.3594x over previous
//
#include <hip/hip_runtime.h>

#define Bsz 1024
#define Tt  256
#define Vv  32004
#define Dd  50
#define Hh  64
#define RR  32   // vocab rows per build_tables block

typedef __bf16 b16x8 __attribute__((ext_vector_type(8)));
typedef float  f32x4 __attribute__((ext_vector_type(4)));

// same-wave LDS ordering fence (no barrier, no vmcnt drain)
__device__ __forceinline__ void lds_fence() {
    asm volatile("s_waitcnt lgkmcnt(0)" ::: "memory");
}
__device__ __forceinline__ float fsig(float x) {
    return __fdividef(1.0f, 1.0f + __expf(-x));
}
__device__ __forceinline__ float ftanh(float x) {
    return 2.0f * __fdividef(1.0f, 1.0f + __expf(-2.0f * x)) - 1.0f;
}

// ---------------------------------------------------------------------------
// Prologue: tab[v][g] = sum_d emb[v][d] * Wih[g][d] + bih[g] + bhh[g]
// round-7 version (best measured): weights in LDS, emb via wave-uniform
// global loads (scalarized/broadcast).
// ---------------------------------------------------------------------------
__launch_bounds__(256, 2)
__global__ void build_tables(const float* __restrict__ emb,
                             const float* __restrict__ Wih1,
                             const float* __restrict__ bih1,
                             const float* __restrict__ bhh1,
                             const float* __restrict__ Wih2,
                             const float* __restrict__ bih2,
                             const float* __restrict__ bhh2,
                             float* __restrict__ tab1,
                             float* __restrict__ tab2) {
    const int v0 = blockIdx.x * RR;
    const int g  = threadIdx.x;
    const int nr = min(RR, Vv - v0);

    const float* Wih = blockIdx.y ? Wih2 : Wih1;
    const float* bih = blockIdx.y ? bih2 : bih1;
    const float* bhh = blockIdx.y ? bhh2 : bhh1;
    float*       tab = blockIdx.y ? tab2 : tab1;

    __shared__ __align__(16) float4 wpack[13 * 256];   // [j][g], 53.2 KB

    {
        const float* wrow = Wih + (size_t)g * Dd;
#pragma unroll
        for (int j = 0; j < 12; ++j) {
            const float2 a = *(const float2*)(wrow + 4 * j);
            const float2 b = *(const float2*)(wrow + 4 * j + 2);
            wpack[j * 256 + g] = make_float4(a.x, a.y, b.x, b.y);
        }
        const float2 t = *(const float2*)(wrow + 48);
        wpack[12 * 256 + g] = make_float4(t.x, t.y, 0.0f, 0.0f);
    }
    __syncthreads();

    const float bias = bih[g] + bhh[g];

    for (int cc = 0; cc < RR / 8; ++cc) {
        const int r0 = cc * 8;
        float acc[8];
#pragma unroll
        for (int r = 0; r < 8; ++r) acc[r] = 0.0f;

#pragma unroll
        for (int j = 0; j < 13; ++j) {
            const float4 wv = wpack[j * 256 + g];
#pragma unroll
            for (int r = 0; r < 8; ++r) {
                const int rv = min(v0 + r0 + r, Vv - 1);
                const float* ep = emb + (size_t)rv * Dd + 4 * j;  // wave-uniform
                if (j < 12) {
                    const float2 e0 = *(const float2*)ep;
                    const float2 e1 = *(const float2*)(ep + 2);
                    acc[r] += e0.x * wv.x + e0.y * wv.y + e1.x * wv.z + e1.y * wv.w;
                } else {
                    const float2 e0 = *(const float2*)ep;      // cols 48,49
                    acc[r] += e0.x * wv.x + e0.y * wv.y;
                }
            }
        }

#pragma unroll
        for (int r = 0; r < 8; ++r) {
            if (r0 + r < nr)
                tab[(size_t)(v0 + r0 + r) * 256 + g] = acc[r] + bias;
        }
    }
}

// ---------------------------------------------------------------------------
// MFMA recurrence v5: ONE WAVE per batch row (1024 blocks x 64 threads).
// Waves are fully independent -> ZERO barriers in the 512-step loop.
// Per step, the wave computes ALL 256 gates of its row:
//   A-operand = h replicated across M (A[m][k]=h[k], one b128 broadcast read
//               per K-half from a wave-private 128B LDS buffer),
//   B-operand = Whh tiles (j=gate-type, hg=hid-group) preloaded in VGPRs
//               (16 tiles x 2 K-halves = 128 VGPRs, bf16),
//   D[m][n] = gate[64j+16hg+n] for EVERY m  ->  lane (q,mn) selects hg=q
//             (3 cndmasks/gate) and owns hid = 16q+mn = lane. Update is
//             register-local, 1 hid/lane, h round-trips wave-private LDS
//             with lgkm fences only. xw fp32 from token table, distance-2
//             register prefetch. __launch_bounds__(64,1) -> 512-VGPR budget.
// ---------------------------------------------------------------------------
__launch_bounds__(64, 1)
__global__ void lstm_main(const int*   __restrict__ s1,
                          const int*   __restrict__ s2,
                          const int*   __restrict__ len1,
                          const int*   __restrict__ len2,
                          const float* __restrict__ tab1,
                          const float* __restrict__ tab2,
                          const float* __restrict__ Whh1,
                          const float* __restrict__ Whh2,
                          const float* __restrict__ Wl1,
                          const float* __restrict__ bl1,
                          const float* __restrict__ Wl2,
                          const float* __restrict__ bl2,
                          float* __restrict__ out) {
    const int lane = threadIdx.x;     // == this lane's hidden unit
    const int q    = lane >> 4;       // MFMA quad
    const int mn   = lane & 15;       // MFMA m/n index
    const int b    = blockIdx.x;      // one batch row per block

    __shared__ __bf16 hws[Hh];        // wave-private h buffer (128 B)
    __shared__ int    tokl[Tt];
    __shared__ float  h2s[Hh];
    __shared__ float  ys[128];

    float c = 0.0f, hval = 0.0f, selh = 0.0f, selc = 0.0f;
    const f32x4 zero4 = {0.0f, 0.0f, 0.0f, 0.0f};

    for (int phase = 0; phase < 2; ++phase) {
        const float* tab  = phase ? tab2 : tab1;
        const float* Whh  = phase ? Whh2 : Whh1;
        const int*   sent = phase ? s2 : s1;
        const int*   lenp = phase ? len2 : len1;

        // ---- stage this row's tokens (wave-private)
#pragma unroll
        for (int i = 0; i < Tt / 64; ++i)
            tokl[lane + 64 * i] = sent[(size_t)b * Tt + lane + 64 * i];

        // ---- B-operand W-frags: wf[j][hg][kh], B[k=32kh+8q+jj][n=mn]
        //      = Whh[64j+16hg+mn][32kh+8q+jj]  (fp32 -> bf16 once per phase)
        b16x8 wf[4][4][2];
#pragma unroll
        for (int j = 0; j < 4; ++j)
#pragma unroll
            for (int hg = 0; hg < 4; ++hg) {
                const int gate = 64 * j + 16 * hg + mn;
#pragma unroll
                for (int kh = 0; kh < 2; ++kh) {
                    const float* ar = Whh + (size_t)gate * Hh + kh * 32 + q * 8;
                    const float4 f0 = *(const float4*)ar;
                    const float4 f1 = *(const float4*)(ar + 4);
                    b16x8 a;
                    a[0] = (__bf16)f0.x; a[1] = (__bf16)f0.y;
                    a[2] = (__bf16)f0.z; a[3] = (__bf16)f0.w;
                    a[4] = (__bf16)f1.x; a[5] = (__bf16)f1.y;
                    a[6] = (__bf16)f1.z; a[7] = (__bf16)f1.w;
                    wf[j][hg][kh] = a;
                }
            }

        const int myidx = lenp[(size_t)b * Hh + lane];

        if (phase) { c = selc; hval = selh; }
        else       { c = 0.0f; hval = 0.0f; }
        selh = 0.0f; selc = 0.0f;
        hws[lane] = (__bf16)hval;
        __syncthreads();          // single wave: cheap; orders tokl + hws

        // ---- xw register prefetch, distance 2
        const float* tabl = tab + lane;
        f32x4 Sa, Sb;
        {
            const int tk0 = tokl[0];
            const float* tr = tabl + (size_t)tk0 * 256;
            Sa[0] = tr[0]; Sa[1] = tr[64]; Sa[2] = tr[128]; Sa[3] = tr[192];
            const int tk1 = tokl[1];
            const float* ts = tabl + (size_t)tk1 * 256;
            Sb[0] = ts[0]; Sb[1] = ts[64]; Sb[2] = ts[128]; Sb[3] = ts[192];
        }

        auto step = [&](int t, f32x4& S) {
            // A-operand: h replicated over M. k=8q+jj (kh0), 32+8q+jj (kh1)
            const b16x8 hf0 = *(const b16x8*)&hws[q * 8];
            const b16x8 hf1 = *(const b16x8*)&hws[32 + q * 8];

            f32x4 ac[4][4];
#pragma unroll
            for (int j = 0; j < 4; ++j)
#pragma unroll
                for (int hg = 0; hg < 4; ++hg) {
                    f32x4 a = __builtin_amdgcn_mfma_f32_16x16x32_bf16(
                                  hf0, wf[j][hg][0], zero4, 0, 0, 0);
                    ac[j][hg] = __builtin_amdgcn_mfma_f32_16x16x32_bf16(
                                  hf1, wf[j][hg][1], a, 0, 0, 0);
                }

            // select hg = q (runtime) -> this lane's 4 gates, hid = lane
            float gg[4];
#pragma unroll
            for (int j = 0; j < 4; ++j) {
                float v = ac[j][0][0];
                v = (q == 1) ? ac[j][1][0] : v;
                v = (q == 2) ? ac[j][2][0] : v;
                v = (q == 3) ? ac[j][3][0] : v;
                gg[j] = v;
            }

            const float gI = gg[0] + S[0];
            const float gF = gg[1] + S[1];
            const float gG = gg[2] + S[2];
            const float gO = gg[3] + S[3];

            // refill S for t+2 (loads survive: no barrier, no vmcnt drain)
            const int tk = tokl[(t + 2 < Tt) ? t + 2 : Tt - 1];
            const float* tr = tabl + (size_t)tk * 256;
            S[0] = tr[0]; S[1] = tr[64]; S[2] = tr[128]; S[3] = tr[192];

            const float iv = fsig(gI);
            const float fv = fsig(gF);
            const float gv = ftanh(gG);
            const float ov = fsig(gO);
            c = fv * c + iv * gv;
            hval = ov * ftanh(c);
            if (t == myidx) { selh = hval; selc = c; }
            hws[lane] = (__bf16)hval;     // publish h for t+1 (same wave)
            lds_fence();                  // lgkm only — no barrier
        };

        for (int t = 0; t < Tt; t += 2) {
            step(t,     Sa);
            step(t + 1, Sb);
        }
    }

    // ---------------- epilogue MLP (this row only) --------------------------
    h2s[lane] = selh;
    __syncthreads();
#pragma unroll
    for (int p = 0; p < 2; ++p) {
        const int n = lane + 64 * p;
        float a = bl1[n];
        const float4* wl = (const float4*)(Wl1 + (size_t)n * 64);
#pragma unroll
        for (int k = 0; k < 16; ++k) {
            const float4 wv = wl[k];
            a += h2s[4 * k] * wv.x + h2s[4 * k + 1] * wv.y +
                 h2s[4 * k + 2] * wv.z + h2s[4 * k + 3] * wv.w;
        }
        ys[n] = ftanh(a);
    }
    __syncthreads();
    if (lane < 4) {
        float a = bl2[lane];
        const float* wl = Wl2 + (size_t)lane * 128;
#pragma unroll 8
        for (int k = 0; k < 128; ++k) a += ys[k] * wl[k];
        out[(size_t)b * 4 + lane] = a;
    }
}

// ---------------------------------------------------------------------------
extern "C" void kernel_launch(void* const* d_in, const int* in_sizes, int n_in,
                              void* d_out, int out_size, void* d_ws, size_t ws_size,
                              hipStream_t stream) {
    const int*   s1   = (const int*)d_in[0];
    const int*   s2   = (const int*)d_in[1];
    const int*   l1   = (const int*)d_in[2];
    const int*   l2   = (const int*)d_in[3];
    // d_in[4], d_in[5] (s1_s, s2_s) unused by the reference
    const float* emb  = (const float*)d_in[6];
    const float* Wih1 = (const float*)d_in[7];
    const float* Whh1 = (const float*)d_in[8];
    const float* bih1 = (const float*)d_in[9];
    const float* bhh1 = (const float*)d_in[10];
    const float* Wih2 = (const float*)d_in[11];
    const float* Whh2 = (const float*)d_in[12];
    const float* bih2 = (const float*)d_in[13];
    const float* bhh2 = (const float*)d_in[14];
    const float* Wl1  = (const float*)d_in[15];
    const float* bl1  = (const float*)d_in[16];
    const float* Wl2  = (const float*)d_in[17];
    const float* bl2  = (const float*)d_in[18];
    float* out = (float*)d_out;

    float* tab1 = (float*)d_ws;                       // [V,256] fp32
    float* tab2 = tab1 + (size_t)Vv * 256;            // [V,256] fp32  (65.6 MB)

    dim3 grid((Vv + RR - 1) / RR, 2);
    build_tables<<<grid, 256, 0, stream>>>(emb, Wih1, bih1, bhh1,
                                           Wih2, bih2, bhh2, tab1, tab2);
    lstm_main<<<Bsz, 64, 0, stream>>>(s1, s2, l1, l2, tab1, tab2,
                                      Whh1, Whh2, Wl1, bl1, Wl2, bl2, out);
}